// Round 9
// baseline (454.339 us; speedup 1.0000x reference)
//
#include <hip/hip_runtime.h>
#include <hip/hip_bf16.h>

// Problem: B=4, S=2048, H=1024, NH=16, DK=64. fp32 I/O.
// R9: barrier-free attention. R8 was LDS-pipe-bound (~85% busy: 26 LDS ops/
// wave/kt). K/V fragments now read directly from global (L2-resident: 1MB/XCD
// working set) as lane-addressed dwordx4 -> LDS pipe only carries the P
// round-trip; zero __syncthreads in the kernel. 32 q-rows/wave (2 B-frags)
// amortizes the full-tile K/V reads 2x. GEMMs unchanged from R8.

typedef __hip_bfloat16 bf16;
typedef __attribute__((ext_vector_type(8))) short bf16x8;  // 8 bf16 = 4 VGPRs
typedef __attribute__((ext_vector_type(4))) float f32x4;

#define B_   4
#define S_   2048
#define H_   1024
#define NH_  16
#define DK_  64
#define M_   8192   // B_*S_
#define N1_  3072
#define K_   1024

#define SCALE_Q 0.18033688f   // 0.125 * log2(e): softmax in exp2 domain

typedef const __attribute__((address_space(1))) void* gas_t;
typedef __attribute__((address_space(3))) void* las_t;
#define G2L16(g, l) __builtin_amdgcn_global_load_lds((gas_t)(g), (las_t)(l), 16, 0, 0)

__device__ __forceinline__ float b2f(bf16 v) { return __bfloat162float(v); }

// pack two fp32 -> two bf16 (RNE, finite inputs), 3 int ops + merge
__device__ __forceinline__ unsigned pk2(float a, float b) {
    unsigned ua = __float_as_uint(a);
    unsigned ub = __float_as_uint(b);
    ua += 0x7FFFu + ((ua >> 16) & 1u);
    ub += 0x7FFFu + ((ub >> 16) & 1u);
    return (ua >> 16) | (ub & 0xFFFF0000u);
}

// ---------------------------------------------------------------------------
// K-1: X fp32 -> bf16 (one-shot; removes cvt from the qkv K-loop)
// ---------------------------------------------------------------------------
__global__ __launch_bounds__(256) void conv_x(const float* __restrict__ X,
                                              bf16* __restrict__ Xb)
{
    size_t i = ((size_t)blockIdx.x * 256 + threadIdx.x) * 8;
    float4 lo = *(const float4*)&X[i];
    float4 hi = *(const float4*)&X[i + 4];
    uint4 u;
    u.x = pk2(lo.x, lo.y); u.y = pk2(lo.z, lo.w);
    u.z = pk2(hi.x, hi.y); u.w = pk2(hi.z, hi.w);
    *(uint4*)&Xb[i] = u;
}

// ---------------------------------------------------------------------------
// K0: convert + transpose weights: W [K][N] fp32 -> WT [N][K] bf16.
// ---------------------------------------------------------------------------
__global__ __launch_bounds__(256) void conv_wT(const float* __restrict__ W,
                                               bf16* __restrict__ WT,
                                               int Kdim, int Ndim)
{
    __shared__ bf16 T[64][72];
    const int tid = threadIdx.x;
    const int n0 = blockIdx.x * 64, k0 = blockIdx.y * 64;
    const int kr = tid >> 4, nc = (tid & 15) * 4;
    #pragma unroll
    for (int p = 0; p < 4; ++p) {
        float4 v = *(const float4*)&W[(size_t)(k0 + kr + p * 16) * Ndim + n0 + nc];
        T[nc + 0][kr + p * 16] = __float2bfloat16(v.x);
        T[nc + 1][kr + p * 16] = __float2bfloat16(v.y);
        T[nc + 2][kr + p * 16] = __float2bfloat16(v.z);
        T[nc + 3][kr + p * 16] = __float2bfloat16(v.w);
    }
    __syncthreads();
    const int nr = tid >> 2, kc = (tid & 3) * 16;
    *(bf16x8*)&WT[(size_t)(n0 + nr) * Kdim + k0 + kc]     = *(const bf16x8*)&T[nr][kc];
    *(bf16x8*)&WT[(size_t)(n0 + nr) * Kdim + k0 + kc + 8] = *(const bf16x8*)&T[nr][kc + 8];
}

// ---------------------------------------------------------------------------
// qkv epilogue shared by both variants
// ---------------------------------------------------------------------------
__device__ __forceinline__ void qkv_epilogue(
    const f32x4 acc[4][4], const float* __restrict__ B1,
    bf16* __restrict__ Qp, bf16* __restrict__ Kp, bf16* __restrict__ Vt,
    int n0, int m0, int wm, int wn, int quad, int col)
{
    const int which = n0 >> 10;          // 0=q 1=k 2=v
    const int bb = m0 >> 11;
    if (which == 2) {
        #pragma unroll
        for (int i = 0; i < 4; ++i) {
            int s = (m0 & (S_ - 1)) + wm * 64 + i * 16 + quad * 4;
            #pragma unroll
            for (int j = 0; j < 4; ++j) {
                int n = n0 + wn * 64 + j * 16 + col;
                int h = (n >> 6) & 15, d = n & 63;
                float bv = B1[n];
                uint2 t;
                t.x = pk2(acc[i][j][0] + bv, acc[i][j][1] + bv);
                t.y = pk2(acc[i][j][2] + bv, acc[i][j][3] + bv);
                *(uint2*)&Vt[(((size_t)(bb * NH_ + h)) * DK_ + d) * S_ + s] = t;
            }
        }
    } else {
        bf16* dst = which ? Kp : Qp;
        const float sc = which ? 1.0f : SCALE_Q;
        #pragma unroll
        for (int i = 0; i < 4; ++i) {
            #pragma unroll
            for (int r = 0; r < 4; ++r) {
                int s = (m0 & (S_ - 1)) + wm * 64 + i * 16 + quad * 4 + r;
                #pragma unroll
                for (int j = 0; j < 4; ++j) {
                    int n = n0 + wn * 64 + j * 16 + col;
                    int h = (n >> 6) & 15, d = n & 63;
                    dst[(((size_t)(bb * NH_ + h)) * S_ + s) * DK_ + d] =
                        __float2bfloat16((acc[i][j][r] + B1[n]) * sc);
                }
            }
        }
    }
}

// ---------------------------------------------------------------------------
// K1-fast: qkv = Xbf @ W1 + b1, pure m97 (G2L16 both operands).
// ---------------------------------------------------------------------------
__global__ __launch_bounds__(256) void gemm_qkv_mfma2(
    const bf16* __restrict__ Xb, const bf16* __restrict__ W1T,
    const float* __restrict__ B1,
    bf16* __restrict__ Qp, bf16* __restrict__ Kp, bf16* __restrict__ Vt)
{
    __shared__ bf16 As[128 * 32];
    __shared__ bf16 Bs[128 * 32];

    const int tid = threadIdx.x;
    const int lane = tid & 63, wv = tid >> 6;
    const int col = lane & 15, quad = lane >> 4;
    const int wm = wv >> 1, wn = wv & 1;
    const int n0 = blockIdx.x * 128, m0 = blockIdx.y * 128;

    f32x4 acc[4][4] = {};

    const bf16* Ag = Xb  + (size_t)m0 * K_;
    const bf16* Bg = W1T + (size_t)n0 * K_;

    for (int k0 = 0; k0 < K_; k0 += 32) {
        #pragma unroll
        for (int h = 0; h < 2; ++h) {
            int idx = tid + h * 256;
            int row = idx >> 2, c = (idx & 3) * 8;
            G2L16(Ag + (size_t)row * K_ + k0 + c, As + (size_t)idx * 8);
            G2L16(Bg + (size_t)row * K_ + k0 + c, Bs + (size_t)idx * 8);
        }
        __syncthreads();

        bf16x8 af[4], bfr[4];
        #pragma unroll
        for (int i = 0; i < 4; ++i)
            af[i] = *(const bf16x8*)&As[(wm * 64 + i * 16 + col) * 32 + quad * 8];
        #pragma unroll
        for (int j = 0; j < 4; ++j)
            bfr[j] = *(const bf16x8*)&Bs[(wn * 64 + j * 16 + col) * 32 + quad * 8];

        #pragma unroll
        for (int i = 0; i < 4; ++i)
            #pragma unroll
            for (int j = 0; j < 4; ++j)
                acc[i][j] = __builtin_amdgcn_mfma_f32_16x16x32_bf16(af[i], bfr[j], acc[i][j], 0, 0, 0);
        __syncthreads();
    }
    qkv_epilogue(acc, B1, Qp, Kp, Vt, n0, m0, wm, wn, quad, col);
}

// ---------------------------------------------------------------------------
// K1-fallback: qkv with in-loop fp32->bf16 A conversion.
// ---------------------------------------------------------------------------
__global__ __launch_bounds__(256) void gemm_qkv_mfma(
    const float* __restrict__ X, const bf16* __restrict__ W1T,
    const float* __restrict__ B1,
    bf16* __restrict__ Qp, bf16* __restrict__ Kp, bf16* __restrict__ Vt)
{
    __shared__ bf16 As[128 * 32];
    __shared__ bf16 Bs[128 * 32];

    const int tid = threadIdx.x;
    const int lane = tid & 63, wv = tid >> 6;
    const int col = lane & 15, quad = lane >> 4;
    const int wm = wv >> 1, wn = wv & 1;
    const int n0 = blockIdx.x * 128, m0 = blockIdx.y * 128;

    f32x4 acc[4][4] = {};

    const float* Ag = X   + (size_t)m0 * K_;
    const bf16*  Bg = W1T + (size_t)n0 * K_;

    for (int k0 = 0; k0 < K_; k0 += 32) {
        #pragma unroll
        for (int h = 0; h < 2; ++h) {
            int idx = tid + h * 256;
            int row = idx >> 2, c = (idx & 3) * 8;
            G2L16(Bg + (size_t)row * K_ + k0 + c, Bs + (size_t)idx * 8);
        }
        #pragma unroll
        for (int h = 0; h < 2; ++h) {
            int idx = tid + h * 256;
            int row = idx >> 2, c = (idx & 3) * 8;
            float4 lo = *(const float4*)&Ag[(size_t)row * K_ + k0 + c];
            float4 hi = *(const float4*)&Ag[(size_t)row * K_ + k0 + c + 4];
            uint4 u;
            u.x = pk2(lo.x, lo.y); u.y = pk2(lo.z, lo.w);
            u.z = pk2(hi.x, hi.y); u.w = pk2(hi.z, hi.w);
            *(uint4*)&As[(size_t)idx * 8] = u;
        }
        __syncthreads();

        bf16x8 af[4], bfr[4];
        #pragma unroll
        for (int i = 0; i < 4; ++i)
            af[i] = *(const bf16x8*)&As[(wm * 64 + i * 16 + col) * 32 + quad * 8];
        #pragma unroll
        for (int j = 0; j < 4; ++j)
            bfr[j] = *(const bf16x8*)&Bs[(wn * 64 + j * 16 + col) * 32 + quad * 8];

        #pragma unroll
        for (int i = 0; i < 4; ++i)
            #pragma unroll
            for (int j = 0; j < 4; ++j)
                acc[i][j] = __builtin_amdgcn_mfma_f32_16x16x32_bf16(af[i], bfr[j], acc[i][j], 0, 0, 0);
        __syncthreads();
    }
    qkv_epilogue(acc, B1, Qp, Kp, Vt, n0, m0, wm, wn, quad, col);
}

// ---------------------------------------------------------------------------
// K2: barrier-free transposed-dataflow MFMA flash attention.
// 256 threads / 4 waves; wave owns 32 q-rows (2 B-frag groups rt=0,1).
// K and V fragments read directly from global (L2-resident, lane-addressed
// dwordx4, 64B-coalesced segments). LDS carries only the per-wave P
// round-trip (C-layout -> B-operand). No __syncthreads anywhere.
//   S^T = K*Q^T ; P = exp2(S^T) ; l = 1^T P (MFMA) ; O^T = Vt*P^T
// ---------------------------------------------------------------------------
__global__ __launch_bounds__(256, 4) void attn_mfma(
    const bf16* __restrict__ Q, const bf16* __restrict__ K,
    const bf16* __restrict__ Vt, bf16* __restrict__ CTX)
{
    __shared__ bf16 Ps[4][32][72];   // per-wave P [q-row-in-wave][c]

    const int tid  = threadIdx.x;
    const int wv   = tid >> 6;       // 0..3
    const int lane = tid & 63;
    const int col  = lane & 15;
    const int quad = lane >> 4;

    const int bh = blockIdx.y;
    const int q0 = blockIdx.x * 128;

    const bf16* Qg  = Q  + (size_t)bh * S_ * DK_;
    const bf16* Kg  = K  + (size_t)bh * S_ * DK_;
    const bf16* Vtg = Vt + (size_t)bh * DK_ * S_;

    const short oneb = (short)0x3F80;
    const bf16x8 ones = {oneb, oneb, oneb, oneb, oneb, oneb, oneb, oneb};

    // Q fragments (B operand): lane(col) holds q-row q0 + wv*32 + rt*16 + col
    bf16x8 qf[2][2];
    #pragma unroll
    for (int rt = 0; rt < 2; ++rt) {
        const int qrow = q0 + wv * 32 + rt * 16 + col;
        qf[rt][0] = *(const bf16x8*)&Qg[(size_t)qrow * DK_ + quad * 8];
        qf[rt][1] = *(const bf16x8*)&Qg[(size_t)qrow * DK_ + 32 + quad * 8];
    }

    f32x4 o[2][4] = {};                 // O^T d-subtiles per rt
    f32x4 l_acc[2] = {f32x4{0,0,0,0}, f32x4{0,0,0,0}};

    for (int kt = 0; kt < S_ / 64; ++kt) {
        const bf16* Kt = Kg + (size_t)(kt * 64) * DK_;

        // S^T = K Q^T : K frags straight from global (transient)
        f32x4 s[2][4];
        #pragma unroll
        for (int cs = 0; cs < 4; ++cs) {
            const bf16* kr = &Kt[(size_t)(cs * 16 + col) * DK_];
            bf16x8 k0 = *(const bf16x8*)&kr[quad * 8];
            bf16x8 k1 = *(const bf16x8*)&kr[32 + quad * 8];
            #pragma unroll
            for (int rt = 0; rt < 2; ++rt) {
                f32x4 a = {0.f, 0.f, 0.f, 0.f};
                a = __builtin_amdgcn_mfma_f32_16x16x32_bf16(k0, qf[rt][0], a, 0, 0, 0);
                a = __builtin_amdgcn_mfma_f32_16x16x32_bf16(k1, qf[rt][1], a, 0, 0, 0);
                s[rt][cs] = a;
            }
        }

        // p = exp2(s) -> packed b64 stores into per-wave LDS
        #pragma unroll
        for (int rt = 0; rt < 2; ++rt)
            #pragma unroll
            for (int cs = 0; cs < 4; ++cs) {
                uint2 p;
                p.x = pk2(exp2f(s[rt][cs][0]), exp2f(s[rt][cs][1]));
                p.y = pk2(exp2f(s[rt][cs][2]), exp2f(s[rt][cs][3]));
                *(uint2*)&Ps[wv][rt * 16 + col][cs * 16 + quad * 4] = p;
            }

        // V frags from global, issued before P consumption for overlap
        bf16x8 vf[4][2];
        #pragma unroll
        for (int ds = 0; ds < 4; ++ds) {
            const bf16* vr = &Vtg[(size_t)(ds * 16 + col) * S_ + kt * 64];
            vf[ds][0] = *(const bf16x8*)&vr[quad * 8];
            vf[ds][1] = *(const bf16x8*)&vr[32 + quad * 8];
        }

        // P back as B-frags (same wave: only lgkmcnt, no barrier)
        bf16x8 pf[2][2];
        #pragma unroll
        for (int rt = 0; rt < 2; ++rt) {
            pf[rt][0] = *(const bf16x8*)&Ps[wv][rt * 16 + col][quad * 8];
            pf[rt][1] = *(const bf16x8*)&Ps[wv][rt * 16 + col][32 + quad * 8];
            // l += 1^T P  (matrix pipe; fills the vmem wait)
            l_acc[rt] = __builtin_amdgcn_mfma_f32_16x16x32_bf16(ones, pf[rt][0], l_acc[rt], 0, 0, 0);
            l_acc[rt] = __builtin_amdgcn_mfma_f32_16x16x32_bf16(ones, pf[rt][1], l_acc[rt], 0, 0, 0);
        }

        // O^T += Vt P^T
        #pragma unroll
        for (int ds = 0; ds < 4; ++ds)
            #pragma unroll
            for (int rt = 0; rt < 2; ++rt) {
                o[rt][ds] = __builtin_amdgcn_mfma_f32_16x16x32_bf16(vf[ds][0], pf[rt][0], o[rt][ds], 0, 0, 0);
                o[rt][ds] = __builtin_amdgcn_mfma_f32_16x16x32_bf16(vf[ds][1], pf[rt][1], o[rt][ds], 0, 0, 0);
            }
    }

    // epilogue: O^T C-layout -> 4 contiguous d per lane -> packed 8B stores
    const int b = bh >> 4, h = bh & 15;
    #pragma unroll
    for (int rt = 0; rt < 2; ++rt) {
        const float inv = 1.f / l_acc[rt][0];
        const int srow = q0 + wv * 32 + rt * 16 + col;
        bf16* crow = CTX + ((size_t)(b * S_ + srow)) * H_ + h * DK_;
        #pragma unroll
        for (int ds = 0; ds < 4; ++ds) {
            uint2 t;
            t.x = pk2(o[rt][ds][0] * inv, o[rt][ds][1] * inv);
            t.y = pk2(o[rt][ds][2] * inv, o[rt][ds][3] * inv);
            *(uint2*)&crow[ds * 16 + quad * 4] = t;
        }
    }
}

// ---------------------------------------------------------------------------
// K3: out = ctx @ W2 + b2 (MFMA).
// ---------------------------------------------------------------------------
__global__ __launch_bounds__(256) void gemm_out_mfma(
    const bf16* __restrict__ Cx, const bf16* __restrict__ W2T,
    const float* __restrict__ B2, float* __restrict__ OUT)
{
    __shared__ bf16 As[128 * 32];
    __shared__ bf16 Bs[128 * 32];

    const int tid = threadIdx.x;
    const int lane = tid & 63, wv = tid >> 6;
    const int col = lane & 15, quad = lane >> 4;
    const int wm = wv >> 1, wn = wv & 1;
    const int n0 = blockIdx.x * 128, m0 = blockIdx.y * 128;

    f32x4 acc[4][4] = {};

    const bf16* Ag = Cx  + (size_t)m0 * K_;
    const bf16* Bg = W2T + (size_t)n0 * K_;

    for (int k0 = 0; k0 < K_; k0 += 32) {
        #pragma unroll
        for (int h = 0; h < 2; ++h) {
            int idx = tid + h * 256;
            int row = idx >> 2, c = (idx & 3) * 8;
            G2L16(Ag + (size_t)row * K_ + k0 + c, As + (size_t)idx * 8);
            G2L16(Bg + (size_t)row * K_ + k0 + c, Bs + (size_t)idx * 8);
        }
        __syncthreads();

        bf16x8 af[4], bfr[4];
        #pragma unroll
        for (int i = 0; i < 4; ++i)
            af[i] = *(const bf16x8*)&As[(wm * 64 + i * 16 + col) * 32 + quad * 8];
        #pragma unroll
        for (int j = 0; j < 4; ++j)
            bfr[j] = *(const bf16x8*)&Bs[(wn * 64 + j * 16 + col) * 32 + quad * 8];

        #pragma unroll
        for (int i = 0; i < 4; ++i)
            #pragma unroll
            for (int j = 0; j < 4; ++j)
                acc[i][j] = __builtin_amdgcn_mfma_f32_16x16x32_bf16(af[i], bfr[j], acc[i][j], 0, 0, 0);
        __syncthreads();
    }

    #pragma unroll
    for (int i = 0; i < 4; ++i) {
        #pragma unroll
        for (int r = 0; r < 4; ++r) {
            int m = m0 + wm * 64 + i * 16 + quad * 4 + r;
            #pragma unroll
            for (int j = 0; j < 4; ++j) {
                int n = n0 + wn * 64 + j * 16 + col;
                OUT[(size_t)m * H_ + n] = acc[i][j][r] + B2[n];
            }
        }
    }
}

// ---------------------------------------------------------------------------
extern "C" void kernel_launch(void* const* d_in, const int* in_sizes, int n_in,
                              void* d_out, int out_size, void* d_ws, size_t ws_size,
                              hipStream_t stream)
{
    const float* X  = (const float*)d_in[0];
    const float* W1 = (const float*)d_in[1];
    const float* B1 = (const float*)d_in[2];
    const float* W2 = (const float*)d_in[3];
    const float* B2 = (const float*)d_in[4];
    float* OUT = (float*)d_out;

    const size_t QE = (size_t)B_ * NH_ * S_ * DK_;   // 8,388,608
    bf16* Qw  = (bf16*)d_ws;
    bf16* Kw  = Qw + QE;
    bf16* Vw  = Kw + QE;        // transposed [bh][d][s]
    bf16* Rw  = Vw + QE;        // W1T during qkv, ctx afterwards
    bf16* W1T = Rw;
    bf16* Cw  = Rw;
    bf16* W2T = Qw;             // overlays Q (dead after attn)
    bf16* Xb  = Rw + QE;        // only if ws permits (5*QE elems total)

    const bool fast = ws_size >= 5 * QE * sizeof(bf16);

    conv_wT<<<dim3(N1_ / 64, K_ / 64), 256, 0, stream>>>(W1, W1T, K_, N1_);
    if (fast) {
        conv_x<<<dim3((int)(QE / (256 * 8))), 256, 0, stream>>>(X, Xb);
        gemm_qkv_mfma2<<<dim3(N1_ / 128, M_ / 128), 256, 0, stream>>>(Xb, W1T, B1, Qw, Kw, Vw);
    } else {
        gemm_qkv_mfma<<<dim3(N1_ / 128, M_ / 128), 256, 0, stream>>>(X, W1T, B1, Qw, Kw, Vw);
    }
    attn_mfma<<<dim3(S_ / 128, B_ * NH_), 256, 0, stream>>>(Qw, Kw, Vw, Cw);
    conv_wT<<<dim3(H_ / 64, K_ / 64), 256, 0, stream>>>(W2, W2T, K_, H_);
    gemm_out_mfma<<<dim3(H_ / 128, M_ / 128), 256, 0, stream>>>(Cw, W2T, B2, OUT);
}